// Round 1
// baseline (547.221 us; speedup 1.0000x reference)
//
#include <hip/hip_runtime.h>
#include <hip/hip_bf16.h>

typedef __attribute__((ext_vector_type(8))) short bf16x8;
typedef __attribute__((ext_vector_type(4))) float f32x4;

#define MFMA(a,b,c) __builtin_amdgcn_mfma_f32_16x16x32_bf16((a),(b),(c),0,0,0)

__device__ __forceinline__ short f2bs(float f){
  union { float f; unsigned u; } x; x.f = f;
  unsigned r = (x.u + 0x7fffu + ((x.u >> 16) & 1u)) >> 16;
  return (short)r;
}

// ---------------- kernel 0: convert weights to bf16 ----------------
__global__ void conv_kernel(const float* xffw, const float* G, const float* w1, const float* w2,
                            short* wqkv_b, short* g_b, short* w1_b, short* w2_b){
  int i = blockIdx.x*blockDim.x + threadIdx.x;
  int stride = gridDim.x*blockDim.x;
  for (int idx = i; idx < 384*128; idx += stride) wqkv_b[idx] = f2bs(xffw[idx]);
  for (int idx = i; idx < 1024*1024; idx += stride) g_b[idx] = f2bs(G[idx]);
  for (int idx = i; idx < 128*128; idx += stride) w1_b[idx] = f2bs(w1[idx]);
  for (int idx = i; idx < 128*128; idx += stride) w2_b[idx] = f2bs(w2[idx]);
}

// ---------------- kernel 1: QKV projection ----------------
// x_[r,j] = sum_d inp[r,d]*W[j,d] + b[j];  q=j<128, k=128..255, v=256..383
// q,k -> bf16 [R][128]; v -> f32 [R][128] and NVT bf16 [bt][c][n]
__global__ __launch_bounds__(256) void qkv_kernel(const float* __restrict__ inp,
                                                  const short* __restrict__ wqkv,
                                                  const float* __restrict__ bias,
                                                  short* __restrict__ q, short* __restrict__ k,
                                                  float* __restrict__ v, short* __restrict__ nvt){
  int wave = threadIdx.x >> 6, lane = threadIdx.x & 63;
  int lr = lane & 15, lg = lane >> 4;
  int r0 = blockIdx.x*64 + wave*16;
  bf16x8 a[4];
  #pragma unroll
  for (int kc=0;kc<4;kc++){
    const float* ar = inp + (size_t)(r0+lr)*128 + kc*32 + lg*8;
    float4 f0 = *(const float4*)ar;
    float4 f1 = *(const float4*)(ar+4);
    bf16x8 t;
    t[0]=f2bs(f0.x); t[1]=f2bs(f0.y); t[2]=f2bs(f0.z); t[3]=f2bs(f0.w);
    t[4]=f2bs(f1.x); t[5]=f2bs(f1.y); t[6]=f2bs(f1.z); t[7]=f2bs(f1.w);
    a[kc]=t;
  }
  f32x4 acc[24];
  #pragma unroll
  for (int j=0;j<24;j++) acc[j] = f32x4{0.f,0.f,0.f,0.f};
  #pragma unroll
  for (int kc=0;kc<4;kc++){
    #pragma unroll
    for (int jt=0;jt<24;jt++){
      bf16x8 b = *(const bf16x8*)(wqkv + (size_t)(jt*16+lr)*128 + kc*32 + lg*8);
      acc[jt] = MFMA(a[kc], b, acc[jt]);
    }
  }
  #pragma unroll
  for (int jt=0;jt<24;jt++){
    int j = jt*16 + lr;
    float bj = bias[j];
    #pragma unroll
    for (int rr=0;rr<4;rr++){
      int R = r0 + lg*4 + rr;
      float val = acc[jt][rr] + bj;
      if (j < 128) q[(size_t)R*128 + j] = f2bs(val);
      else if (j < 256) k[(size_t)R*128 + (j-128)] = f2bs(val);
      else {
        int c = j - 256;
        v[(size_t)R*128 + c] = val;
        int bt = R >> 10, n = R & 1023;
        nvt[((size_t)bt*128 + c)*1024 + n] = f2bs(val);
      }
    }
  }
}

// ---------------- kernel 2: KGT[bt][m][d] = (K^T G)[d][m] / sqrt(128) ----------------
__global__ __launch_bounds__(256) void kg_kernel(const short* __restrict__ kb,
                                                 const short* __restrict__ gb,
                                                 short* __restrict__ kgt){
  __shared__ __align__(16) short k_ldsT[128][56];  // [d][n], pad for banks, 112B rows (16B mult)
  __shared__ __align__(16) short g_ldsT[64][56];   // [m_local][n]
  int bt = blockIdx.x >> 4;
  int mt = blockIdx.x & 15;
  int mbase = mt*64;
  int tid = threadIdx.x;
  int wave = tid>>6, lane = tid&63, lr = lane&15, lg = lane>>4;
  f32x4 acc[8];
  #pragma unroll
  for (int i=0;i<8;i++) acc[i] = f32x4{0.f,0.f,0.f,0.f};
  for (int nc=0; nc<32; nc++){
    __syncthreads();
    {
      int n = tid>>3, d0 = (tid&7)*16;
      const short* src = kb + ((size_t)(bt*1024 + nc*32 + n))*128 + d0;
      bf16x8 v0 = *(const bf16x8*)src;
      bf16x8 v1 = *(const bf16x8*)(src+8);
      #pragma unroll
      for (int j=0;j<8;j++) k_ldsT[d0+j][n] = v0[j];
      #pragma unroll
      for (int j=0;j<8;j++) k_ldsT[d0+8+j][n] = v1[j];
    }
    {
      int n = tid>>3, m0 = (tid&7)*8;
      const short* src = gb + ((size_t)(nc*32 + n))*1024 + mbase + m0;
      bf16x8 v0 = *(const bf16x8*)src;
      #pragma unroll
      for (int j=0;j<8;j++) g_ldsT[m0+j][n] = v0[j];
    }
    __syncthreads();
    bf16x8 bf = *(const bf16x8*)&g_ldsT[wave*16+lr][lg*8];
    #pragma unroll
    for (int dt=0;dt<8;dt++){
      bf16x8 af = *(const bf16x8*)&k_ldsT[dt*16+lr][lg*8];
      acc[dt] = MFMA(af, bf, acc[dt]);
    }
  }
  const float SCALE = 0.08838834764831845f; // 1/sqrt(128)
  int m = mbase + wave*16 + lr;
  #pragma unroll
  for (int dt=0;dt<8;dt++){
    #pragma unroll
    for (int rr=0;rr<4;rr++){
      int d = dt*16 + lg*4 + rr;
      kgt[((size_t)(bt*1024 + m))*128 + d] = f2bs(acc[dt][rr]*SCALE);
    }
  }
}

// ---------------- kernel 3: softmax stats (rowmax, rowZ) + col-sum partials at t=5 ----------------
__global__ __launch_bounds__(256) void stats_kernel(const short* __restrict__ q,
                                                    const short* __restrict__ kgt,
                                                    float* __restrict__ rmax, float* __restrict__ rz,
                                                    float* __restrict__ cspart){
  __shared__ float e_lds[16][1024];
  __shared__ float s_rmax[16], s_rinvz[16];
  int bt = blockIdx.x >> 6;      // /64
  int rblk = blockIdx.x & 63;
  int wave = threadIdx.x>>6, lane = threadIdx.x&63, lr = lane&15, lg = lane>>4;
  int r0 = rblk*16;
  bf16x8 a[4];
  const short* qrow = q + ((size_t)(bt*1024 + r0 + lr))*128;
  #pragma unroll
  for (int kc=0;kc<4;kc++) a[kc] = *(const bf16x8*)(qrow + kc*32 + lg*8);
  #pragma unroll
  for (int mtt=0; mtt<16; mtt++){
    int m0 = wave*256 + mtt*16;
    f32x4 acc = f32x4{0.f,0.f,0.f,0.f};
    #pragma unroll
    for (int kc=0;kc<4;kc++){
      bf16x8 b = *(const bf16x8*)(kgt + ((size_t)(bt*1024 + m0 + lr))*128 + kc*32 + lg*8);
      acc = MFMA(a[kc], b, acc);
    }
    #pragma unroll
    for (int rr=0;rr<4;rr++) e_lds[lg*4+rr][m0+lr] = acc[rr];
  }
  __syncthreads();
  int row = threadIdx.x >> 4, l16 = threadIdx.x & 15;
  float mx = -1e30f;
  for (int j=0;j<64;j++) mx = fmaxf(mx, e_lds[row][l16 + j*16]);
  #pragma unroll
  for (int m=1;m<16;m<<=1) mx = fmaxf(mx, __shfl_xor(mx, m, 64));
  float z = 0.f;
  for (int j=0;j<64;j++) z += __expf(e_lds[row][l16 + j*16] - mx);
  #pragma unroll
  for (int m=1;m<16;m<<=1) z += __shfl_xor(z, m, 64);
  if (l16==0){
    rmax[(size_t)bt*1024 + r0 + row] = mx;
    rz  [(size_t)bt*1024 + r0 + row] = z;
    s_rmax[row] = mx;
    s_rinvz[row] = 1.0f/z;
  }
  int t = bt % 12, b = bt / 12;
  if (t == 5){
    __syncthreads();
    for (int mm = threadIdx.x; mm < 1024; mm += 256){
      float s = 0.f;
      #pragma unroll
      for (int r=0;r<16;r++) s += __expf(e_lds[r][mm] - s_rmax[r]) * s_rinvz[r];
      cspart[((size_t)(b*64 + rblk))*1024 + mm] = s;
    }
  }
}

// ---------------- kernel 4: deterministic top-2 smallest col_sums -> y per batch ----------------
__global__ void top2_kernel(const float* __restrict__ cspart, int* __restrict__ yidx){
  __shared__ float cv1[256], cv2[256];
  __shared__ int   ci1[256], ci2[256];
  int b = blockIdx.x;
  float bv1 = 3.4e38f, bv2 = 3.4e38f;
  int bi1 = 0x7fffffff, bi2 = 0x7fffffff;
  for (int m = threadIdx.x; m < 1024; m += 256){
    float s = 0.f;
    for (int blk = 0; blk < 64; blk++) s += cspart[((size_t)(b*64 + blk))*1024 + m];
    if (s < bv1 || (s == bv1 && m < bi1)) { bv2 = bv1; bi2 = bi1; bv1 = s; bi1 = m; }
    else if (s < bv2 || (s == bv2 && m < bi2)) { bv2 = s; bi2 = m; }
  }
  cv1[threadIdx.x]=bv1; ci1[threadIdx.x]=bi1;
  cv2[threadIdx.x]=bv2; ci2[threadIdx.x]=bi2;
  __syncthreads();
  if (threadIdx.x == 0){
    float v1 = 3.4e38f, v2 = 3.4e38f; int i1 = 0x7fffffff, i2 = 0x7fffffff;
    for (int tn = 0; tn < 512; tn++){
      float v = (tn < 256) ? cv1[tn] : cv2[tn-256];
      int   i = (tn < 256) ? ci1[tn] : ci2[tn-256];
      if (i == 0x7fffffff) continue;
      if (v < v1 || (v == v1 && i < i1)) { v2=v1; i2=i1; v1=v; i1=i; }
      else if (v < v2 || (v == v2 && i < i2)) { v2=v; i2=i; }
    }
    yidx[b] = i2;
  }
}

// ---------------- kernel 5: NV fixup (mixup region) ----------------
__global__ void nvfix_kernel(const float* __restrict__ v, const int* __restrict__ yidx,
                             short* __restrict__ nvt){
  int bt = blockIdx.x; int b = bt/12, t = bt%12;
  int y = yidx[b];
  int y_start = max(y-6, 0), y_end = min(y+12, 1024);
  int bs, j0, cnt;
  if (y_end > 1024-6){ bs = 1; j0 = y_start; cnt = y_end - y_start; }
  else { bs = 6; j0 = y_start/6; cnt = y_end/6 - j0; }
  int items = bs*78;
  int idx = threadIdx.x;
  if (idx >= items) return;
  int i = idx / 78, c = idx % 78;
  float acc = 0.f;
  for (int jj=0;jj<cnt;jj++){
    int col = (j0+jj)*bs + i;
    float gv;
    if (t == 5 && col == y){
      float wsum = 0.f, mv = 0.f;
      #pragma unroll
      for (int tp=0;tp<5;tp++){
        float d = (float)tp - 4.0f;
        float w = __expf(-d*d/200.0f);
        wsum += w;
        mv += w * v[((size_t)(b*12+tp)*1024 + y)*128 + c];
      }
      gv = mv / wsum;
    } else {
      gv = v[((size_t)bt*1024 + col)*128 + c];
    }
    acc += gv;
  }
  float avg = acc / (float)cnt;
  int ti = (int)avg;                 // trunc toward zero (numpy float->int)
  unsigned char u = (unsigned char)ti;  // wrap mod 256
  nvt[((size_t)bt*128 + c)*1024 + (y+i)] = f2bs((float)u);
}

// ---------------- kernel 6: vi = softmax(e') @ NV  (split-softmax recompute) ----------------
__global__ __launch_bounds__(256) void vi_kernel(const short* __restrict__ q,
                                                 const short* __restrict__ kgt,
                                                 const short* __restrict__ nvt,
                                                 const float* __restrict__ rmax,
                                                 const float* __restrict__ rz,
                                                 float* __restrict__ vi){
  __shared__ __align__(16) short p_lds[4][16][48]; // [wave][row][m-chunk 32 + pad]
  int bt = blockIdx.x >> 4;
  int rblk = blockIdx.x & 15;
  int wave = threadIdx.x>>6, lane = threadIdx.x&63, lr = lane&15, lg = lane>>4;
  int r0 = rblk*64 + wave*16;
  bf16x8 a[4];
  const short* qrow = q + ((size_t)(bt*1024 + r0 + lr))*128;
  #pragma unroll
  for (int kc=0;kc<4;kc++) a[kc] = *(const bf16x8*)(qrow + kc*32 + lg*8);
  float rmx[4], riz[4];
  #pragma unroll
  for (int rr=0;rr<4;rr++){
    size_t R = (size_t)bt*1024 + r0 + lg*4 + rr;
    rmx[rr] = rmax[R];
    riz[rr] = 1.0f / rz[R];
  }
  f32x4 acc[8];
  #pragma unroll
  for (int i=0;i<8;i++) acc[i] = f32x4{0.f,0.f,0.f,0.f};
  for (int mc=0; mc<32; mc++){
    int m0 = mc*32;
    #pragma unroll
    for (int s=0;s<2;s++){
      f32x4 e = f32x4{0.f,0.f,0.f,0.f};
      #pragma unroll
      for (int kc=0;kc<4;kc++){
        bf16x8 b = *(const bf16x8*)(kgt + ((size_t)(bt*1024 + m0 + s*16 + lr))*128 + kc*32 + lg*8);
        e = MFMA(a[kc], b, e);
      }
      #pragma unroll
      for (int rr=0;rr<4;rr++){
        float p = __expf(e[rr] - rmx[rr]) * riz[rr];
        p_lds[wave][lg*4+rr][s*16+lr] = f2bs(p);
      }
    }
    __syncthreads();
    bf16x8 pa = *(const bf16x8*)&p_lds[wave][lr][lg*8];
    #pragma unroll
    for (int ct=0; ct<8; ct++){
      bf16x8 b = *(const bf16x8*)(nvt + ((size_t)bt*128 + ct*16+lr)*1024 + m0 + lg*8);
      acc[ct] = MFMA(pa, b, acc[ct]);
    }
    __syncthreads();
  }
  #pragma unroll
  for (int ct=0;ct<8;ct++){
    #pragma unroll
    for (int rr=0;rr<4;rr++){
      vi[((size_t)(bt*1024 + r0 + lg*4 + rr))*128 + ct*16 + lr] = acc[ct][rr];
    }
  }
}

// ---------------- kernel 7: FFN (gelu) + residual + LayerNorm ----------------
__global__ __launch_bounds__(256) void ffn_kernel(const float* __restrict__ vi,
                                                  const float* __restrict__ inp,
                                                  const short* __restrict__ w1b,
                                                  const short* __restrict__ w2b,
                                                  const float* __restrict__ b1,
                                                  const float* __restrict__ b2,
                                                  const float* __restrict__ lnw,
                                                  const float* __restrict__ lnb,
                                                  float* __restrict__ out){
  __shared__ __align__(16) short h_lds[4][16][144];
  int wave = threadIdx.x>>6, lane = threadIdx.x&63, lr = lane&15, lg = lane>>4;
  int r0 = blockIdx.x*64 + wave*16;
  bf16x8 a[4];
  #pragma unroll
  for (int kc=0;kc<4;kc++){
    const float* ar = vi + (size_t)(r0+lr)*128 + kc*32 + lg*8;
    float4 f0 = *(const float4*)ar;
    float4 f1 = *(const float4*)(ar+4);
    bf16x8 tv;
    tv[0]=f2bs(f0.x); tv[1]=f2bs(f0.y); tv[2]=f2bs(f0.z); tv[3]=f2bs(f0.w);
    tv[4]=f2bs(f1.x); tv[5]=f2bs(f1.y); tv[6]=f2bs(f1.z); tv[7]=f2bs(f1.w);
    a[kc]=tv;
  }
  f32x4 acc[8];
  #pragma unroll
  for (int i=0;i<8;i++) acc[i] = f32x4{0.f,0.f,0.f,0.f};
  #pragma unroll
  for (int kc=0;kc<4;kc++){
    #pragma unroll
    for (int jt=0;jt<8;jt++){
      bf16x8 b = *(const bf16x8*)(w1b + (size_t)(jt*16+lr)*128 + kc*32 + lg*8);
      acc[jt] = MFMA(a[kc], b, acc[jt]);
    }
  }
  #pragma unroll
  for (int jt=0;jt<8;jt++){
    float bj = b1[jt*16+lr];
    #pragma unroll
    for (int rr=0;rr<4;rr++){
      float x = acc[jt][rr] + bj;
      float g = 0.5f*x*(1.0f + erff(x*0.70710678118654752f));
      h_lds[wave][lg*4+rr][jt*16+lr] = f2bs(g);
    }
  }
  __syncthreads();
  bf16x8 ha[4];
  #pragma unroll
  for (int kc=0;kc<4;kc++) ha[kc] = *(const bf16x8*)&h_lds[wave][lr][kc*32 + lg*8];
  f32x4 acc2[8];
  #pragma unroll
  for (int i=0;i<8;i++) acc2[i] = f32x4{0.f,0.f,0.f,0.f};
  #pragma unroll
  for (int kc=0;kc<4;kc++){
    #pragma unroll
    for (int jt=0;jt<8;jt++){
      bf16x8 b = *(const bf16x8*)(w2b + (size_t)(jt*16+lr)*128 + kc*32 + lg*8);
      acc2[jt] = MFMA(ha[kc], b, acc2[jt]);
    }
  }
  float xv[8][4];
  #pragma unroll
  for (int jt=0;jt<8;jt++){
    float bj = b2[jt*16+lr];
    #pragma unroll
    for (int rr=0;rr<4;rr++){
      xv[jt][rr] = acc2[jt][rr] + bj + inp[(size_t)(r0 + lg*4 + rr)*128 + jt*16 + lr];
    }
  }
  float mu[4], rstd[4];
  #pragma unroll
  for (int rr=0;rr<4;rr++){
    float s = 0.f;
    #pragma unroll
    for (int jt=0;jt<8;jt++) s += xv[jt][rr];
    #pragma unroll
    for (int m=1;m<16;m<<=1) s += __shfl_xor(s, m, 64);
    mu[rr] = s * (1.0f/128.0f);
  }
  #pragma unroll
  for (int rr=0;rr<4;rr++){
    float s = 0.f;
    #pragma unroll
    for (int jt=0;jt<8;jt++){ float d = xv[jt][rr]-mu[rr]; s += d*d; }
    #pragma unroll
    for (int m=1;m<16;m<<=1) s += __shfl_xor(s, m, 64);
    rstd[rr] = rsqrtf(s * (1.0f/128.0f) + 1e-5f);
  }
  #pragma unroll
  for (int jt=0;jt<8;jt++){
    int col = jt*16 + lr;
    float lw = lnw[col], lb = lnb[col];
    #pragma unroll
    for (int rr=0;rr<4;rr++){
      out[(size_t)(r0 + lg*4 + rr)*128 + col] = (xv[jt][rr]-mu[rr])*rstd[rr]*lw + lb;
    }
  }
}

// ---------------- host launch ----------------
extern "C" void kernel_launch(void* const* d_in, const int* in_sizes, int n_in,
                              void* d_out, int out_size, void* d_ws, size_t ws_size,
                              hipStream_t stream) {
  (void)in_sizes; (void)n_in; (void)out_size;
  const float* inp  = (const float*)d_in[0];
  const float* G    = (const float*)d_in[1];
  const float* xffw = (const float*)d_in[2];
  const float* xffb = (const float*)d_in[3];
  const float* w1   = (const float*)d_in[4];
  const float* b1   = (const float*)d_in[5];
  const float* w2   = (const float*)d_in[6];
  const float* b2   = (const float*)d_in[7];
  const float* lnw  = (const float*)d_in[8];
  const float* lnb  = (const float*)d_in[9];
  float* out = (float*)d_out;
  char* ws = (char*)d_ws;

  size_t off = 0;
  auto take = [&](size_t bytes)->char*{ char* p = ws + off; off += (bytes + 255) & ~(size_t)255; return p; };
  short* wqkv_b = (short*)take(384*128*2);
  short* g_b    = (short*)take((size_t)1024*1024*2);
  short* w1_b   = (short*)take(128*128*2);
  short* w2_b   = (short*)take(128*128*2);
  short* qb     = (short*)take((size_t)48*1024*128*2);
  short* kb     = (short*)take((size_t)48*1024*128*2);
  float* vf     = (float*)take((size_t)48*1024*128*4);
  short* nvt    = (short*)take((size_t)48*128*1024*2);
  short* kgt    = (short*)take((size_t)48*1024*128*2);
  float* rmax   = (float*)take((size_t)48*1024*4);
  float* rz     = (float*)take((size_t)48*1024*4);
  float* cspart = (float*)take((size_t)4*64*1024*4);
  int*   yidx   = (int*)take(256);
  float* vibuf  = (float*)take((size_t)48*1024*128*4);
  if (off > ws_size) return; // workspace too small; will show as zero-output failure

  conv_kernel<<<dim3(512), dim3(256), 0, stream>>>(xffw, G, w1, w2, wqkv_b, g_b, w1_b, w2_b);
  qkv_kernel<<<dim3(768), dim3(256), 0, stream>>>(inp, wqkv_b, xffb, qb, kb, vf, nvt);
  kg_kernel<<<dim3(768), dim3(256), 0, stream>>>(kb, g_b, kgt);
  stats_kernel<<<dim3(3072), dim3(256), 0, stream>>>(qb, kgt, rmax, rz, cspart);
  top2_kernel<<<dim3(4), dim3(256), 0, stream>>>(cspart, yidx);
  nvfix_kernel<<<dim3(48), dim3(512), 0, stream>>>(vf, yidx, nvt);
  vi_kernel<<<dim3(768), dim3(256), 0, stream>>>(qb, kgt, nvt, rmax, rz, vibuf);
  ffn_kernel<<<dim3(768), dim3(256), 0, stream>>>(vibuf, inp, w1_b, w2_b, b1, b2, lnw, lnb, out);
}